// Round 11
// baseline (261.925 us; speedup 1.0000x reference)
//
#include <hip/hip_runtime.h>
#include <hip/hip_bf16.h>
#include <math.h>

#define T_SEQ 4096
#define C_DIM 1024
#define H_HEADS 16
#define D_HEAD 64
#define QKVW 3072
#define WIN_HALF 128
#define GLOBAL_TOK 32

typedef __attribute__((ext_vector_type(8))) short bf16x8;
typedef __attribute__((ext_vector_type(4))) float f32x4;

__device__ __forceinline__ float bf2f(unsigned short u) {
    union { unsigned int i; float f; } c; c.i = ((unsigned int)u) << 16; return c.f;
}
__device__ __forceinline__ unsigned short f2bf(float f) {
    union { float f; unsigned int i; } c; c.f = f;
    return (unsigned short)((c.i + 0x7fffu + ((c.i >> 16) & 1u)) >> 16);
}

__device__ __forceinline__ void gll16(const unsigned short* g, unsigned short* l) {
    __builtin_amdgcn_global_load_lds(
        (const __attribute__((address_space(1))) void*)g,
        (__attribute__((address_space(3))) void*)l, 16, 0, 0);
}

// f32 -> bf16 (RNE), vectorized x4. n4 = n/4.
__global__ __launch_bounds__(256) void cvt_f32_bf16_kernel(
    const float* __restrict__ src, unsigned short* __restrict__ dst, int n4)
{
    int idx = blockIdx.x * 256 + threadIdx.x;
    if (idx < n4) {
        float4 v = ((const float4*)src)[idx];
        ushort4 o;
        o.x = f2bf(v.x); o.y = f2bf(v.y); o.z = f2bf(v.z); o.w = f2bf(v.w);
        ((ushort4*)dst)[idx] = o;
    }
}

// W [R][Ncols] f32  ->  Wt [Ncols][R] bf16  (32x32 tiles via LDS)
__global__ __launch_bounds__(256) void cvt_transpose_kernel(
    const float* __restrict__ src, unsigned short* __restrict__ dst,
    int R, int Ncols)
{
    __shared__ unsigned short tile[32][36];
    const int r0 = blockIdx.y * 32, c0 = blockIdx.x * 32;
    const int t = threadIdx.x;
    const int rr = t >> 3, cq = (t & 7) * 4;
    float4 v = *(const float4*)(src + (size_t)(r0 + rr) * Ncols + c0 + cq);
    tile[rr][cq + 0] = f2bf(v.x); tile[rr][cq + 1] = f2bf(v.y);
    tile[rr][cq + 2] = f2bf(v.z); tile[rr][cq + 3] = f2bf(v.w);
    __syncthreads();
    const int cc = t >> 3, rq = (t & 7) * 4;
    ushort4 o;
    o.x = tile[rq + 0][cc]; o.y = tile[rq + 1][cc];
    o.z = tile[rq + 2][cc]; o.w = tile[rq + 3][cc];
    *(ushort4*)(dst + (size_t)(c0 + cc) * R + r0 + rq) = o;
}

// V slice of qkv [T][2048 + vcol] (bf16) -> vT [vcol][T] (bf16), 32x32 tiles.
__global__ __launch_bounds__(256) void transpose_v_kernel(
    const unsigned short* __restrict__ qkv, unsigned short* __restrict__ vT)
{
    __shared__ unsigned short tile[32][36];
    const int c0 = blockIdx.x * 32;   // vcol
    const int t0 = blockIdx.y * 32;   // token
    const int t = threadIdx.x;
    const int rr = t >> 3, cq = (t & 7) * 4;
    ushort4 v = *(const ushort4*)(qkv + (size_t)(t0 + rr) * QKVW + 2 * C_DIM + c0 + cq);
    tile[rr][cq + 0] = v.x; tile[rr][cq + 1] = v.y;
    tile[rr][cq + 2] = v.z; tile[rr][cq + 3] = v.w;
    __syncthreads();
    const int cc = t >> 3, rq = (t & 7) * 4;
    ushort4 o;
    o.x = tile[rq + 0][cc]; o.y = tile[rq + 1][cc];
    o.z = tile[rq + 2][cc]; o.w = tile[rq + 3][cc];
    *(ushort4*)(vT + (size_t)(c0 + cc) * T_SEQ + t0 + rq) = o;
}

// C[m,n] = sum_k A[m,k]*Bt[n,k] + bias[n]; m97 recipe (unchanged r7-r10).
template<int OUT_BF16>
__global__ __launch_bounds__(256) void gemm_nt_kernel(
    const unsigned short* __restrict__ A,    // [M,K]
    const unsigned short* __restrict__ Bt,   // [N,K]
    const float* __restrict__ bias,          // [N]
    void* __restrict__ Cv, int M, int N, int K)
{
    __shared__ unsigned short As[128 * 32];
    __shared__ unsigned short Bs[128 * 32];
    const int tid = threadIdx.x;
    const int w = tid >> 6, lane = tid & 63;
    const int quad = lane >> 4, r16 = lane & 15;
    const int m0 = blockIdx.y * 128, n0 = blockIdx.x * 128;
    const int wm = (w & 1) * 64, wn = (w >> 1) * 64;

    f32x4 acc[4][4];
    #pragma unroll
    for (int i = 0; i < 4; ++i)
        #pragma unroll
        for (int j = 0; j < 4; ++j) acc[i][j] = (f32x4){0.f, 0.f, 0.f, 0.f};

    const unsigned short* Ab = A + (size_t)m0 * K;
    const unsigned short* Bb = Bt + (size_t)n0 * K;

    for (int k0 = 0; k0 < K; k0 += 32) {
        __syncthreads();
        #pragma unroll
        for (int i = 0; i < 2; ++i) {
            const int chunk = w * 128 + i * 64 + lane;
            const int row = chunk >> 2, kc = (chunk & 3) * 8;
            gll16(Ab + (size_t)row * K + k0 + kc, &As[(w * 2 + i) * 512]);
            gll16(Bb + (size_t)row * K + k0 + kc, &Bs[(w * 2 + i) * 512]);
        }
        asm volatile("s_waitcnt vmcnt(0)" ::: "memory");
        __syncthreads();

        bf16x8 af[4], bf_[4];
        #pragma unroll
        for (int t = 0; t < 4; ++t) {
            af[t]  = *(const bf16x8*)&As[(wm + t * 16 + r16) * 32 + quad * 8];
            bf_[t] = *(const bf16x8*)&Bs[(wn + t * 16 + r16) * 32 + quad * 8];
        }
        #pragma unroll
        for (int mt = 0; mt < 4; ++mt)
            #pragma unroll
            for (int nt = 0; nt < 4; ++nt)
                acc[mt][nt] = __builtin_amdgcn_mfma_f32_16x16x32_bf16(
                    af[mt], bf_[nt], acc[mt][nt], 0, 0, 0);
    }

    #pragma unroll
    for (int nt = 0; nt < 4; ++nt) {
        const int col = n0 + wn + nt * 16 + r16;
        const float bv = bias[col];
        #pragma unroll
        for (int mt = 0; mt < 4; ++mt)
            #pragma unroll
            for (int reg = 0; reg < 4; ++reg) {
                const int row = m0 + wm + mt * 16 + quad * 4 + reg;
                if (OUT_BF16)
                    ((unsigned short*)Cv)[(size_t)row * N + col] = f2bf(acc[mt][nt][reg] + bv);
                else
                    ((float*)Cv)[(size_t)row * N + col] = acc[mt][nt][reg] + bv;
            }
    }
}

// MFMA flash attention, S^T formulation, SINGLE-PASS softmax per wave.
// Each wave: <=2 64-col tiles -> one 128-col softmax (no online rescale),
// one PV sweep (K=128). Normal block = (head, 16-row tile): 4 waves split
// the ~7 tiles {w, w+4}, then LDS merge of (m,l,O) -> y (1 barrier).
// Dense blocks (rows 0-31, all-valid): (head, rt, chunk): 4 waves x 128
// cols of a 512-col chunk; each wave emits partial slot chunk*4+w (no
// barrier); merged by attn_combine. Absent/masked tiles: addresses clamped
// to col 0 (finite data), scores forced -inf -> P exactly 0.
// XCD swizzle: h = bid & 15.
#define PT_STRIDE 132
#define NSLOT 32
#define PROW 72
__global__ __launch_bounds__(256) void sparse_attn_mfma(
    const unsigned short* __restrict__ qkv,
    const unsigned short* __restrict__ vT,
    unsigned short* __restrict__ y,
    float* __restrict__ part)
{
    // union: P-buffer (4 waves x 16 x 132 ushort = 16896B) / merge buffer
    // (Om 4x64x16 f32 = 16384B + Ml 4x16x2 f32 = 512B) — P dead before merge
    __shared__ __align__(16) char smem[16896];
    unsigned short* PtBase = (unsigned short*)smem;
    float* Om = (float*)smem;            // [w][lane][16]
    float* Ml = Om + 4096;               // [w][16][2]

    const int tid = threadIdx.x;
    const int w = tid >> 6, lane = tid & 63;
    const int quad = lane >> 4, n = lane & 15;
    const int bid = blockIdx.x;
    const int nNormal = H_HEADS * 254;   // 4064

    int h, rowbase, chunk = -1, rt = 0;
    if (bid < nNormal) {
        h = bid & 15;
        rowbase = (2 + (bid >> 4)) * 16;
    } else {
        const int idx = bid - nNormal;   // [0,256)
        h = idx & 15;
        const int u = idx >> 4;          // [0,16)
        rt = u & 1; chunk = u >> 1;      // chunk in [0,8)
        rowbase = rt * 16;
    }
    const bool dense = chunk >= 0;
    const int row = rowbase + n;

    // tile assignment (<=2 tiles of 64 cols, single softmax pass)
    int c0s[2]; bool val[2];
    if (dense) {
        c0s[0] = chunk * 512 + w * 128; c0s[1] = c0s[0] + 64;
        val[0] = val[1] = true;
    } else {
        int t0 = (rowbase - WIN_HALF) & ~63; if (t0 < 64) t0 = 64;
        const int wlo = t0;
        int whi = rowbase + 16 + WIN_HALF; if (whi > T_SEQ) whi = T_SEQ;
        const int n_tiles = 1 + (whi - wlo + 63) / 64;   // <= 7
        #pragma unroll
        for (int j = 0; j < 2; ++j) {
            const int it = w + 4 * j;
            val[j] = it < n_tiles;
            c0s[j] = !val[j] ? 0 : (it == 0 ? 0 : wlo + (it - 1) * 64);
        }
    }

    // Q B-frags: B[n=qrow][k=d]
    const unsigned short* qp = qkv + (size_t)row * QKVW + h * 64 + quad * 8;
    bf16x8 q0 = *(const bf16x8*)qp;
    bf16x8 q1 = *(const bf16x8*)(qp + 32);

    const unsigned short* kb = qkv + C_DIM + h * 64;
    const unsigned short* vb = vT + (size_t)h * 64 * T_SEQ;
    unsigned short* myPt = PtBase + w * 16 * PT_STRIDE;

    // ---- S^T = K Q^T for both tiles ----
    const f32x4 Z = (f32x4){0.f, 0.f, 0.f, 0.f};
    f32x4 St[2][4];
    #pragma unroll
    for (int j = 0; j < 2; ++j) {
        const unsigned short* kr = kb + (size_t)(c0s[j] + n) * QKVW + quad * 8;
        #pragma unroll
        for (int g = 0; g < 4; ++g) {
            bf16x8 klo = *(const bf16x8*)(kr + (size_t)(g * 16) * QKVW);
            bf16x8 khi = *(const bf16x8*)(kr + (size_t)(g * 16) * QKVW + 32);
            St[j][g] = __builtin_amdgcn_mfma_f32_16x16x32_bf16(klo, q0, Z, 0, 0, 0);
            St[j][g] = __builtin_amdgcn_mfma_f32_16x16x32_bf16(khi, q1, St[j][g], 0, 0, 0);
        }
    }
    // ---- V^T A-frags issued early (consumed after softmax) ----
    bf16x8 vf[2][2][4];   // [tile][half][dblk]
    #pragma unroll
    for (int j = 0; j < 2; ++j) {
        const unsigned short* vr = vb + (size_t)n * T_SEQ + c0s[j] + quad * 8;
        #pragma unroll
        for (int d = 0; d < 4; ++d) {
            vf[j][0][d] = *(const bf16x8*)(vr + (size_t)(d * 16) * T_SEQ);
            vf[j][1][d] = *(const bf16x8*)(vr + (size_t)(d * 16) * T_SEQ + 32);
        }
    }

    // ---- mask + single-pass softmax over 128 cols ----
    float mm = -INFINITY;
    #pragma unroll
    for (int j = 0; j < 2; ++j)
        #pragma unroll
        for (int g = 0; g < 4; ++g)
            #pragma unroll
            for (int r = 0; r < 4; ++r) {
                float v = St[j][g][r] * 0.125f;
                bool ok = val[j];
                if (!dense) {
                    const int col = c0s[j] + g * 16 + quad * 4 + r;
                    int dd = row - col; dd = dd < 0 ? -dd : dd;
                    ok = ok && (col < GLOBAL_TOK || dd <= WIN_HALF);
                }
                v = ok ? v : -INFINITY;
                St[j][g][r] = v;
                mm = fmaxf(mm, v);
            }
    mm = fmaxf(mm, __shfl_xor(mm, 16));
    mm = fmaxf(mm, __shfl_xor(mm, 32));
    const float mnf = (mm == -INFINITY) ? 0.f : mm;
    float rs = 0.f;
    #pragma unroll
    for (int j = 0; j < 2; ++j)
        #pragma unroll
        for (int g = 0; g < 4; ++g) {
            float e0 = __expf(St[j][g][0] - mnf);
            float e1 = __expf(St[j][g][1] - mnf);
            float e2 = __expf(St[j][g][2] - mnf);
            float e3 = __expf(St[j][g][3] - mnf);
            rs += (e0 + e1) + (e2 + e3);
            unsigned long long pk =
                (unsigned long long)f2bf(e0) |
                ((unsigned long long)f2bf(e1) << 16) |
                ((unsigned long long)f2bf(e2) << 32) |
                ((unsigned long long)f2bf(e3) << 48);
            *(unsigned long long*)&myPt[n * PT_STRIDE + j * 64 + g * 16 + quad * 4] = pk;
        }
    rs += __shfl_xor(rs, 16);
    rs += __shfl_xor(rs, 32);

    asm volatile("s_waitcnt lgkmcnt(0)" ::: "memory");
    // ---- PV: O^T = V^T(A) x P(B), K=128 ----
    f32x4 O[4];
    #pragma unroll
    for (int i = 0; i < 4; ++i) O[i] = (f32x4){0.f, 0.f, 0.f, 0.f};
    #pragma unroll
    for (int kg = 0; kg < 4; ++kg) {
        bf16x8 pf = *(const bf16x8*)&myPt[n * PT_STRIDE + kg * 32 + quad * 8];
        #pragma unroll
        for (int d = 0; d < 4; ++d)
            O[d] = __builtin_amdgcn_mfma_f32_16x16x32_bf16(
                vf[kg >> 1][kg & 1][d], pf, O[d], 0, 0, 0);
    }

    if (dense) {
        const int slot = chunk * 4 + w;
        float* pb = part + ((size_t)(h * 2 + rt) * NSLOT + slot) * 16 * PROW;
        #pragma unroll
        for (int dblk = 0; dblk < 4; ++dblk)
            #pragma unroll
            for (int r = 0; r < 4; ++r)
                pb[n * PROW + dblk * 16 + quad * 4 + r] = O[dblk][r];
        if (quad == 0) {
            pb[n * PROW + 64] = mm;
            pb[n * PROW + 65] = rs;
        }
    } else {
        // cross-wave merge via LDS (P-buffer dead; reuse as Om/Ml)
        __syncthreads();   // all waves done reading their Pt
        #pragma unroll
        for (int dblk = 0; dblk < 4; ++dblk)
            #pragma unroll
            for (int r = 0; r < 4; ++r)
                Om[(w * 64 + lane) * 16 + dblk * 4 + r] = O[dblk][r];
        if (quad == 0) {
            Ml[(w * 16 + n) * 2 + 0] = mm;
            Ml[(w * 16 + n) * 2 + 1] = rs;
        }
        __syncthreads();
        if (w == 0) {
            float M = -INFINITY;
            #pragma unroll
            for (int ww = 0; ww < 4; ++ww)
                M = fmaxf(M, Ml[(ww * 16 + n) * 2 + 0]);
            float e[4], L = 0.f;
            #pragma unroll
            for (int ww = 0; ww < 4; ++ww) {
                e[ww] = __expf(Ml[(ww * 16 + n) * 2 + 0] - M);
                L += Ml[(ww * 16 + n) * 2 + 1] * e[ww];
            }
            const float invL = 1.f / L;
            unsigned short* yr = y + (size_t)row * C_DIM + h * 64;
            #pragma unroll
            for (int dblk = 0; dblk < 4; ++dblk) {
                #pragma unroll
                for (int rp = 0; rp < 2; ++rp) {
                    float v0 = 0.f, v1 = 0.f;
                    #pragma unroll
                    for (int ww = 0; ww < 4; ++ww) {
                        v0 += Om[(ww * 64 + lane) * 16 + dblk * 4 + rp * 2 + 0] * e[ww];
                        v1 += Om[(ww * 64 + lane) * 16 + dblk * 4 + rp * 2 + 1] * e[ww];
                    }
                    const unsigned int pk = (unsigned int)f2bf(v0 * invL) |
                                            ((unsigned int)f2bf(v1 * invL) << 16);
                    *(unsigned int*)&yr[dblk * 16 + quad * 4 + rp * 2] = pk;
                }
            }
        }
    }
}

// Merge NSLOT partials per (head, 16-row tile) -> y rows 0..31.
__global__ __launch_bounds__(64) void attn_combine(
    const float* __restrict__ part, unsigned short* __restrict__ y)
{
    const int d = threadIdx.x;
    const int h = blockIdx.x >> 1, rt = blockIdx.x & 1;
    const float* base = part + (size_t)(h * 2 + rt) * NSLOT * 16 * PROW;
    for (int row = 0; row < 16; ++row) {
        float M = -INFINITY;
        for (int sl = 0; sl < NSLOT; ++sl)
            M = fmaxf(M, base[(size_t)sl * 16 * PROW + row * PROW + 64]);
        float L = 0.f, Od = 0.f;
        for (int sl = 0; sl < NSLOT; ++sl) {
            const float* p = base + (size_t)sl * 16 * PROW + row * PROW;
            const float s = __expf(p[64] - M);
            L += p[65] * s;
            Od += p[d] * s;
        }
        y[(size_t)(rt * 16 + row) * C_DIM + h * 64 + d] = f2bf(Od / L);
    }
}

extern "C" void kernel_launch(void* const* d_in, const int* in_sizes, int n_in,
                              void* d_out, int out_size, void* d_ws, size_t ws_size,
                              hipStream_t stream) {
    const float* x  = (const float*)d_in[0];
    const float* Wa = (const float*)d_in[1];
    const float* ba = (const float*)d_in[2];
    const float* Wp = (const float*)d_in[3];
    const float* bp = (const float*)d_in[4];
    float* out = (float*)d_out;

    // ws (ushort units): xb 4M, Wabt 3M, Wpbt 1M, qkv 12M, yat 4M = 48 MiB
    unsigned short* xb   = (unsigned short*)d_ws;                   // [4096,1024]
    unsigned short* Wabt = xb   + (size_t)T_SEQ * C_DIM;            // [3072,1024]
    unsigned short* Wpbt = Wabt + (size_t)C_DIM * QKVW;             // [1024,1024]
    unsigned short* qkv  = Wpbt + (size_t)C_DIM * C_DIM;            // [4096,3072]
    unsigned short* yat  = qkv  + (size_t)T_SEQ * QKVW;             // [4096,1024]
    // overlays (dead after gemm1): vT on xb (8 MiB), part on Wabt (4.7 MB)
    unsigned short* vT = xb;
    float* part = (float*)Wabt;

    const int n_x = T_SEQ * C_DIM;
    cvt_f32_bf16_kernel<<<n_x / 4 / 256, 256, 0, stream>>>(x, xb, n_x / 4);
    cvt_transpose_kernel<<<dim3(QKVW / 32, C_DIM / 32), 256, 0, stream>>>(
        Wa, Wabt, C_DIM, QKVW);
    cvt_transpose_kernel<<<dim3(C_DIM / 32, C_DIM / 32), 256, 0, stream>>>(
        Wp, Wpbt, C_DIM, C_DIM);

    gemm_nt_kernel<1><<<dim3(QKVW / 128, T_SEQ / 128), 256, 0, stream>>>(
        xb, Wabt, ba, qkv, T_SEQ, QKVW, C_DIM);

    transpose_v_kernel<<<dim3(C_DIM / 32, T_SEQ / 32), 256, 0, stream>>>(qkv, vT);

    const int nBlocks = H_HEADS * 254 + 256;   // 4064 normal + 256 dense
    sparse_attn_mfma<<<nBlocks, 256, 0, stream>>>(qkv, vT, yat, part);
    attn_combine<<<H_HEADS * 2, 64, 0, stream>>>(part, yat);

    gemm_nt_kernel<0><<<dim3(C_DIM / 128, T_SEQ / 128), 256, 0, stream>>>(
        yat, Wpbt, bp, out, T_SEQ, C_DIM, C_DIM);
}